// Round 7
// baseline (278.926 us; speedup 1.0000x reference)
//
#include <hip/hip_runtime.h>

#define S_LEN 2048
#define DMODEL 1024
#define H_CNT 16
#define DK 64
#define BATCH 4

typedef __attribute__((ext_vector_type(8))) short short8;
typedef __attribute__((ext_vector_type(4))) float f32x4;
typedef __attribute__((ext_vector_type(16))) float f32x16;

static __device__ __forceinline__ short f2bf(float f) {
  union { float f; unsigned u; } x; x.f = f;
  unsigned r = x.u + 0x7fffu + ((x.u >> 16) & 1u);
  return (short)(r >> 16);
}

static __device__ __forceinline__ unsigned cvt_pk_bf16(float lo, float hi) {
  unsigned r;
  asm("v_cvt_pk_bf16_f32 %0, %1, %2" : "=v"(r) : "v"(lo), "v"(hi));
  return r;
}

static __device__ __forceinline__ void gl_lds16(const short* g, short* l) {
  __builtin_amdgcn_global_load_lds((const __attribute__((address_space(1))) void*)g,
                                   (__attribute__((address_space(3))) void*)l, 16, 0, 0);
}

// ---------------- cast fp32 -> bf16, 8 elems/thread ----------------
__global__ __launch_bounds__(256) void cast_kernel(const float* __restrict__ src,
                                                   short* __restrict__ dst, int n8) {
  int i = blockIdx.x * 256 + threadIdx.x;
  if (i >= n8) return;
  const float4* s4 = (const float4*)src;
  float4 a = s4[2 * i], b = s4[2 * i + 1];
  short8 o;
  o[0] = f2bf(a.x); o[1] = f2bf(a.y); o[2] = f2bf(a.z); o[3] = f2bf(a.w);
  o[4] = f2bf(b.x); o[5] = f2bf(b.y); o[6] = f2bf(b.z); o[7] = f2bf(b.w);
  ((short8*)dst)[i] = o;
}

// ---------------- GEMM v2 (known-good since r6) ----------------
// 128x64 tile, BK=32, 4 waves, global_load_lds 16B staging, XCD swizzle.
// MODE 0: A=x, B=w. out bf16 -> (B,H,S,dk). bias[col], then *scl.  (Q, K)
// MODE 1: A=w, B=x. out bf16 -> (B,H,dk,S) = V^T. bias[row].       (V)
// MODE 2: A=attn, B=w. out fp32 row-major [M,N]. bias[col].        (final)
// grid MUST be 1024 blocks; MODE1: M=1024,N=8192; else M=8192,N=1024.
template <int MODE>
__global__ __launch_bounds__(256) void gemm_bt(const short* __restrict__ A,
                                               const short* __restrict__ B,
                                               const float* __restrict__ bias,
                                               void* __restrict__ Cout,
                                               int M, int N, int K, float scl) {
  __shared__ short Sab[(128 + 64) * 32];  // As: rows 0..127, Bs: rows 128..191
  const int tid = threadIdx.x;
  const int lane = tid & 63, wid = tid >> 6;
  const int lin = blockIdx.x;
  const int w = (lin & 7) * 128 + (lin >> 3);
  int bx, by;
  if (MODE == 1) { bx = w >> 3; by = w & 7; }
  else           { bx = w & 15; by = w >> 4; }
  const int m0 = by * 128, n0 = bx * 64;
  const int wr = wid * 32;
  const int lrow = lane & 15, lk8 = (lane >> 4) * 8;

  const int l4 = lane >> 2, lc = (lane & 3) * 8;
  const short* gsrc[3];
  short* ldst[3];
#pragma unroll
  for (int i = 0; i < 3; i++) {
    int c = wid * 3 + i;
    ldst[i] = &Sab[c * 512];
    if (c < 8) gsrc[i] = &A[(size_t)(m0 + c * 16 + l4) * K + lc];
    else       gsrc[i] = &B[(size_t)(n0 + (c - 8) * 16 + l4) * K + lc];
  }

  f32x4 acc[2][4] = {};

  for (int k0 = 0; k0 < K; k0 += 32) {
#pragma unroll
    for (int i = 0; i < 3; i++) gl_lds16(gsrc[i] + k0, ldst[i]);
    __syncthreads();
    short8 af[2], bfr[4];
#pragma unroll
    for (int m = 0; m < 2; m++) af[m] = *(const short8*)(&Sab[(wr + m * 16 + lrow) * 32 + lk8]);
#pragma unroll
    for (int n = 0; n < 4; n++) bfr[n] = *(const short8*)(&Sab[(128 + n * 16 + lrow) * 32 + lk8]);
#pragma unroll
    for (int m = 0; m < 2; m++)
#pragma unroll
      for (int n = 0; n < 4; n++)
        acc[m][n] = __builtin_amdgcn_mfma_f32_16x16x32_bf16(af[m], bfr[n], acc[m][n], 0, 0, 0);
    __syncthreads();
  }

  const int g4 = (lane >> 4) * 4;
#pragma unroll
  for (int n = 0; n < 4; n++) {
    const int col = n0 + n * 16 + lrow;
#pragma unroll
    for (int m = 0; m < 2; m++) {
#pragma unroll
      for (int i = 0; i < 4; i++) {
        const int row = m0 + wr + m * 16 + g4 + i;
        float val = acc[m][n][i];
        if (MODE == 0) {
          val = (val + bias[col]) * scl;
          int b = row >> 11, s2 = row & 2047, h = col >> 6, d = col & 63;
          ((short*)Cout)[((size_t)(b * H_CNT + h) * S_LEN + s2) * DK + d] = f2bf(val);
        } else if (MODE == 1) {
          val = val + bias[row];
          int h = row >> 6, d = row & 63, b = col >> 11, s2 = col & 2047;
          ((short*)Cout)[((size_t)(b * H_CNT + h) * DK + d) * S_LEN + s2] = f2bf(val);
        } else {
          val = val + bias[col];
          ((float*)Cout)[(size_t)row * N + col] = val;
        }
      }
    }
  }
}

// ---------------- causal flash attention v4 ----------------
// r6 body with: (a) per-wave balanced pairing — wave owns q-tiles {p, 63-p},
// processed sequentially, so EVERY wave does exactly 65 kv-iterations;
// (b) K-tile register double-buffer (clamped prefetch of t+1).
// grid: dim3(16, B*H) natural 2-D (NO blockIdx remap), block 128 = 2 waves.
// p = blockIdx.x*2 + wid in [0,32).
__global__ __launch_bounds__(128, 2) void attn2_kernel(const short* __restrict__ Q,
                                                       const short* __restrict__ Kc,
                                                       const short* __restrict__ Vt,
                                                       short* __restrict__ Oout) {
  const int bh = blockIdx.y;
  const int wid = threadIdx.x >> 6, lane = threadIdx.x & 63;
  const int p = blockIdx.x * 2 + wid;
  const int ql = lane & 31, hl = lane >> 5;

  const short* Qb = Q + (size_t)bh * S_LEN * DK;
  const short* Kb = Kc + (size_t)bh * S_LEN * DK;
  const short* Vb = Vt + (size_t)bh * DK * S_LEN;
  const int b = bh >> 4, h = bh & 15;

  for (int phase = 0; phase < 2; ++phase) {
    const int qt = phase ? (63 - p) : p;
    const int q0 = qt * 32;

    short8 qf[4];
#pragma unroll
    for (int kk = 0; kk < 4; kk++)
      qf[kk] = *(const short8*)(&Qb[(q0 + ql) * DK + kk * 16 + hl * 8]);

    f32x16 oacc[2] = {};
    float mr = -1e30f, lr = 0.f;

    // K register double-buffer: preload tile 0
    short8 kf[4];
#pragma unroll
    for (int kk = 0; kk < 4; kk++)
      kf[kk] = *(const short8*)(&Kb[ql * DK + kk * 16 + hl * 8]);

    const int ntiles = qt + 1;
    for (int t = 0; t < ntiles; t++) {
      const int kv0 = t * 32;
      // issue prefetch of next K tile (clamped: last iter re-reads current)
      const int kvn = (t + 1 < ntiles) ? kv0 + 32 : kv0;
      short8 kfn[4];
#pragma unroll
      for (int kk = 0; kk < 4; kk++)
        kfn[kk] = *(const short8*)(&Kb[(kvn + ql) * DK + kk * 16 + hl * 8]);
      // issue V loads for this tile (consumed after softmax, ~300cy later)
      short8 vf[2][2];
#pragma unroll
      for (int td = 0; td < 2; td++)
#pragma unroll
        for (int kk = 0; kk < 2; kk++)
          vf[td][kk] = *(const short8*)(&Vb[(size_t)(td * 32 + ql) * S_LEN + kv0 + kk * 16 + hl * 8]);

      // S^T[kv, q] = sum_k K[kv,k] * Q[q,k]  — kf already resident
      f32x16 st = {};
#pragma unroll
      for (int kk = 0; kk < 4; kk++)
        st = __builtin_amdgcn_mfma_f32_32x32x16_bf16(kf[kk], qf[kk], st, 0, 0, 0);

      float pv[16];
#pragma unroll
      for (int r = 0; r < 16; r++) pv[r] = st[r];
      if (t == ntiles - 1) {
#pragma unroll
        for (int r = 0; r < 16; r++) {
          int kvr = (r & 3) + 8 * (r >> 2) + 4 * hl;
          if (kvr > ql) pv[r] = -1e30f;
        }
      }
      float pm = pv[0];
#pragma unroll
      for (int r = 1; r < 16; r++) pm = fmaxf(pm, pv[r]);
      pm = fmaxf(pm, __shfl_xor(pm, 32, 64));
      if (!__all(pm <= mr + 8.f)) {
        float mnew = fmaxf(mr, pm);
        float al = __builtin_amdgcn_exp2f(mr - mnew);
        lr *= al;
#pragma unroll
        for (int td = 0; td < 2; td++)
#pragma unroll
          for (int r = 0; r < 16; r++) oacc[td][r] *= al;
        mr = mnew;
      }
      float rs = 0.f;
#pragma unroll
      for (int r = 0; r < 16; r++) {
        pv[r] = __builtin_amdgcn_exp2f(pv[r] - mr);
        rs += pv[r];
      }
      rs += __shfl_xor(rs, 32, 64);
      lr += rs;

      unsigned wpk[8];
#pragma unroll
      for (int tt = 0; tt < 8; tt++) wpk[tt] = cvt_pk_bf16(pv[2 * tt], pv[2 * tt + 1]);
      union { short8 s; unsigned u[4]; } bf0, bf1;
      {
        unsigned xa = __shfl_xor((int)wpk[2], 32, 64), xb = __shfl_xor((int)wpk[0], 32, 64);
        bf0.u[0] = hl ? xa : wpk[0];
        bf0.u[2] = hl ? wpk[2] : xb;
      }
      {
        unsigned xa = __shfl_xor((int)wpk[3], 32, 64), xb = __shfl_xor((int)wpk[1], 32, 64);
        bf0.u[1] = hl ? xa : wpk[1];
        bf0.u[3] = hl ? wpk[3] : xb;
      }
      {
        unsigned xa = __shfl_xor((int)wpk[6], 32, 64), xb = __shfl_xor((int)wpk[4], 32, 64);
        bf1.u[0] = hl ? xa : wpk[4];
        bf1.u[2] = hl ? wpk[6] : xb;
      }
      {
        unsigned xa = __shfl_xor((int)wpk[7], 32, 64), xb = __shfl_xor((int)wpk[5], 32, 64);
        bf1.u[1] = hl ? xa : wpk[5];
        bf1.u[3] = hl ? wpk[7] : xb;
      }

#pragma unroll
      for (int td = 0; td < 2; td++) {
        oacc[td] = __builtin_amdgcn_mfma_f32_32x32x16_bf16(vf[td][0], bf0.s, oacc[td], 0, 0, 0);
        oacc[td] = __builtin_amdgcn_mfma_f32_32x32x16_bf16(vf[td][1], bf1.s, oacc[td], 0, 0, 0);
      }

      // rotate K double-buffer
#pragma unroll
      for (int kk = 0; kk < 4; kk++) kf[kk] = kfn[kk];
    }

    const float inv = __builtin_amdgcn_rcpf(lr);
    unsigned* ob = (unsigned*)Oout + ((size_t)b * S_LEN + q0 + ql) * (DMODEL / 2) + h * (DK / 2);
#pragma unroll
    for (int td = 0; td < 2; td++)
#pragma unroll
      for (int tt = 0; tt < 8; tt++) {
        unsigned pkv = cvt_pk_bf16(oacc[td][2 * tt] * inv, oacc[td][2 * tt + 1] * inv);
        ob[td * 16 + (tt & 1) + 4 * (tt >> 1) + 2 * hl] = pkv;
      }
  }
}

// ---------------- launcher ----------------
extern "C" void kernel_launch(void* const* d_in, const int* in_sizes, int n_in,
                              void* d_out, int out_size, void* d_ws, size_t ws_size,
                              hipStream_t stream) {
  (void)in_sizes; (void)n_in; (void)out_size; (void)ws_size;
  const float* query = (const float*)d_in[0];
  const float* key_i = (const float*)d_in[1];
  const float* value = (const float*)d_in[2];
  const float* w_q = (const float*)d_in[4];
  const float* b_q = (const float*)d_in[5];
  const float* w_k = (const float*)d_in[6];
  const float* b_k = (const float*)d_in[7];
  const float* w_v = (const float*)d_in[8];
  const float* b_v = (const float*)d_in[9];
  const float* w_o = (const float*)d_in[10];
  const float* b_o = (const float*)d_in[11];

  const size_t XE = (size_t)BATCH * S_LEN * DMODEL;  // 8388608
  const size_t WE = (size_t)DMODEL * DMODEL;         // 1048576

  short* xq = (short*)d_ws;
  short* xk = xq + XE;
  short* xv = xk + XE;
  short* wq = xv + XE;
  short* wk = wq + WE;
  short* wv = wk + WE;
  short* wo = wv + WE;
  short* qb = wo + WE;
  short* kb = qb + XE;
  short* vtb = kb + XE;
  short* attnb = xq;  // reuse: xq dead after Q projection

  const int M = BATCH * S_LEN;  // 8192

  int n8x = (int)(XE / 8), n8w = (int)(WE / 8);
  cast_kernel<<<dim3((n8x + 255) / 256), 256, 0, stream>>>(query, xq, n8x);
  cast_kernel<<<dim3((n8x + 255) / 256), 256, 0, stream>>>(key_i, xk, n8x);
  cast_kernel<<<dim3((n8x + 255) / 256), 256, 0, stream>>>(value, xv, n8x);
  cast_kernel<<<dim3((n8w + 255) / 256), 256, 0, stream>>>(w_q, wq, n8w);
  cast_kernel<<<dim3((n8w + 255) / 256), 256, 0, stream>>>(w_k, wk, n8w);
  cast_kernel<<<dim3((n8w + 255) / 256), 256, 0, stream>>>(w_v, wv, n8w);
  cast_kernel<<<dim3((n8w + 255) / 256), 256, 0, stream>>>(w_o, wo, n8w);

  // Q pre-scaled by 1/sqrt(dk) * log2(e): attention works in exp2 domain
  const float qscale = 0.125f * 1.44269504088896f;

  gemm_bt<0><<<1024, 256, 0, stream>>>(xq, wq, b_q, qb, M, DMODEL, DMODEL, qscale);
  gemm_bt<0><<<1024, 256, 0, stream>>>(xk, wk, b_k, kb, M, DMODEL, DMODEL, 1.f);
  gemm_bt<1><<<1024, 256, 0, stream>>>(wv, xv, b_v, vtb, DMODEL, M, DMODEL, 1.f);

  attn2_kernel<<<dim3(16, BATCH * H_CNT), 128, 0, stream>>>(qb, kb, vtb, attnb);

  gemm_bt<2><<<1024, 256, 0, stream>>>(attnb, wo, b_o, d_out, M, DMODEL, DMODEL, 1.f);
}